// Round 1
// baseline (848.966 us; speedup 1.0000x reference)
//
#include <hip/hip_runtime.h>

#define N_NODES 100000
#define N_EDGES 1600000
#define F_NODE  32
#define F_GLOB  16
#define HDIM    64
#define OUTDIM  64

// ---------- CSR build ----------

__global__ void k_hist(const int* __restrict__ dst, int* __restrict__ cnt) {
    int e = blockIdx.x * blockDim.x + threadIdx.x;
    if (e < N_EDGES) atomicAdd(&cnt[dst[e]], 1);
}

__global__ void k_dis(const int* __restrict__ cnt, float* __restrict__ dis) {
    int v = blockIdx.x * blockDim.x + threadIdx.x;
    if (v < N_NODES) dis[v] = rsqrtf((float)(cnt[v] + 1));  // +1 self-loop
}

__global__ void k_scan1(const int* __restrict__ cnt, int* __restrict__ rowptr,
                        int* __restrict__ bsum) {
    __shared__ int lds[256];
    int t = threadIdx.x;
    int i = blockIdx.x * 256 + t;
    int v = (i < N_NODES) ? cnt[i] : 0;
    int x = v;
    lds[t] = x;
    __syncthreads();
    for (int ofs = 1; ofs < 256; ofs <<= 1) {
        int y = (t >= ofs) ? lds[t - ofs] : 0;
        __syncthreads();
        x += y;
        lds[t] = x;
        __syncthreads();
    }
    if (i < N_NODES) rowptr[i] = x - v;        // block-local exclusive
    if (t == 255)    bsum[blockIdx.x] = x;     // block total
}

__global__ void k_scan2(int* __restrict__ bsum, int nb, int* __restrict__ rowptr) {
    __shared__ int lds[512];
    int t = threadIdx.x;
    int v = (t < nb) ? bsum[t] : 0;
    int x = v;
    lds[t] = x;
    __syncthreads();
    for (int ofs = 1; ofs < 512; ofs <<= 1) {
        int y = (t >= ofs) ? lds[t - ofs] : 0;
        __syncthreads();
        x += y;
        lds[t] = x;
        __syncthreads();
    }
    if (t < nb) bsum[t] = x - v;               // exclusive over block totals
    if (t == 0) rowptr[N_NODES] = N_EDGES;
}

__global__ void k_scan3(int* __restrict__ rowptr, const int* __restrict__ bsum) {
    int i = blockIdx.x * 256 + threadIdx.x;
    if (i < N_NODES) rowptr[i] += bsum[blockIdx.x];
}

__global__ void k_scatter(const int* __restrict__ src, const int* __restrict__ dst,
                          const int* __restrict__ rowptr, int* __restrict__ fill,
                          const float* __restrict__ dis,
                          int* __restrict__ col, float* __restrict__ wgt) {
    int e = blockIdx.x * blockDim.x + threadIdx.x;
    if (e < N_EDGES) {
        int d = dst[e], s = src[e];
        int pos = rowptr[d] + atomicAdd(&fill[d], 1);
        col[pos] = s;
        wgt[pos] = dis[s] * dis[d];            // full symmetric norm
    }
}

// ---------- dense kernels ----------

// h = x @ w_node + b_node   (K=32)
__global__ void __launch_bounds__(256)
k_embed(const float* __restrict__ x, const float* __restrict__ w,
        const float* __restrict__ b, float* __restrict__ h) {
    __shared__ float wl[F_NODE * HDIM];   // 8 KB
    __shared__ float xl[4 * F_NODE];
    int t = threadIdx.x;
    for (int i = t; i < F_NODE * HDIM; i += 256) wl[i] = w[i];
    int row0 = blockIdx.x * 4;
    if (t < 4 * F_NODE) {
        int r = t / F_NODE, k = t % F_NODE;
        int rr = row0 + r;
        xl[t] = (rr < N_NODES) ? x[rr * F_NODE + k] : 0.f;
    }
    __syncthreads();
    int r = t >> 6, c = t & 63;
    int row = row0 + r;
    if (row < N_NODES) {
        float acc = b[c];
        #pragma unroll
        for (int k = 0; k < F_NODE; ++k) acc += xl[r * F_NODE + k] * wl[k * HDIM + c];
        h[row * HDIM + c] = acc;
    }
}

// hw = h @ w   (64x64 weights in LDS, 4 rows/block)
__global__ void __launch_bounds__(256)
k_gemm64(const float* __restrict__ h, const float* __restrict__ w,
         float* __restrict__ hw) {
    __shared__ float wl[HDIM * HDIM];     // 16 KB
    __shared__ float xl[4 * HDIM];
    int t = threadIdx.x;
    for (int i = t; i < HDIM * HDIM; i += 256) wl[i] = w[i];
    int row0 = blockIdx.x * 4;
    {
        int r = t >> 6, k = t & 63;
        int rr = row0 + r;
        xl[t] = (rr < N_NODES) ? h[rr * HDIM + k] : 0.f;
    }
    __syncthreads();
    int r = t >> 6, c = t & 63;
    int row = row0 + r;
    if (row < N_NODES) {
        float acc = 0.f;
        #pragma unroll
        for (int k = 0; k < HDIM; ++k) acc += xl[r * HDIM + k] * wl[k * HDIM + c];
        hw[row * HDIM + c] = acc;
    }
}

// pull aggregation: one wave per node, lane = feature
__global__ void __launch_bounds__(256)
k_pull(const float* __restrict__ hw, const int* __restrict__ rowptr,
       const int* __restrict__ col, const float* __restrict__ wgt,
       const float* __restrict__ dis, const float* __restrict__ b,
       float* __restrict__ hout) {
    int wid = threadIdx.x >> 6, lane = threadIdx.x & 63;
    int v = blockIdx.x * 4 + wid;
    if (v >= N_NODES) return;
    float d = dis[v];
    float acc = b[lane] + d * d * hw[(size_t)v * HDIM + lane];  // self-loop
    int s0 = rowptr[v], s1 = rowptr[v + 1];
    for (int base = s0; base < s1; base += 64) {
        int m = s1 - base; if (m > 64) m = 64;
        int c = 0; float wv = 0.f;
        if (lane < m) { c = col[base + lane]; wv = wgt[base + lane]; }
        for (int i = 0; i < m; ++i) {
            int   cs = __shfl(c, i);
            float ws = __shfl(wv, i);
            acc += ws * hw[(size_t)cs * HDIM + lane];
        }
    }
    hout[(size_t)v * HDIM + lane] = fmaxf(acc, 0.f);
}

// ---------- readout ----------

__global__ void k_mean(const float* __restrict__ h, float* __restrict__ partial) {
    __shared__ float lds[256];
    int t = threadIdx.x;
    int f = t & 63, g = t >> 6;
    float acc = 0.f;
    for (int v = blockIdx.x * 4 + g; v < N_NODES; v += gridDim.x * 4)
        acc += h[(size_t)v * HDIM + f];
    lds[t] = acc;
    __syncthreads();
    if (t < 64)
        partial[blockIdx.x * 64 + t] = lds[t] + lds[t + 64] + lds[t + 128] + lds[t + 192];
}

__global__ void k_final(const float* __restrict__ partial, int nparts,
                        const float* __restrict__ gfeat,
                        const float* __restrict__ wg, const float* __restrict__ bg,
                        const float* __restrict__ w1, const float* __restrict__ b1,
                        const float* __restrict__ w2, const float* __restrict__ b2,
                        float* __restrict__ out) {
    __shared__ float xc[2 * HDIM];
    __shared__ float hid[HDIM];
    int t = threadIdx.x;   // 64 threads
    float s = 0.f;
    for (int p = 0; p < nparts; ++p) s += partial[p * 64 + t];
    xc[t] = s / (float)N_NODES;                       // x_graph
    float gacc = bg[t];
    for (int k = 0; k < F_GLOB; ++k) gacc += gfeat[k] * wg[k * HDIM + t];
    xc[HDIM + t] = fmaxf(gacc, 0.f);                  // x_global
    __syncthreads();
    float hacc = b1[t];
    for (int k = 0; k < 2 * HDIM; ++k) hacc += xc[k] * w1[k * HDIM + t];
    hid[t] = fmaxf(hacc, 0.f);
    __syncthreads();
    float oacc = b2[t];
    for (int k = 0; k < HDIM; ++k) oacc += hid[k] * w2[k * OUTDIM + t];
    out[t] = oacc;
}

// ---------- launch ----------

extern "C" void kernel_launch(void* const* d_in, const int* in_sizes, int n_in,
                              void* d_out, int out_size, void* d_ws, size_t ws_size,
                              hipStream_t stream) {
    const float* x      = (const float*)d_in[0];
    const int*   eidx   = (const int*)d_in[1];
    const float* gfeat  = (const float*)d_in[2];
    const float* w_node = (const float*)d_in[3];
    const float* b_node = (const float*)d_in[4];
    const float* w_glob = (const float*)d_in[5];
    const float* b_glob = (const float*)d_in[6];
    const float* w_c[3] = {(const float*)d_in[7], (const float*)d_in[9], (const float*)d_in[11]};
    const float* b_c[3] = {(const float*)d_in[8], (const float*)d_in[10], (const float*)d_in[12]};
    const float* w_fc1  = (const float*)d_in[13];
    const float* b_fc1  = (const float*)d_in[14];
    const float* w_fc2  = (const float*)d_in[15];
    const float* b_fc2  = (const float*)d_in[16];
    float* out = (float*)d_out;

    const int* srcp = eidx;
    const int* dstp = eidx + N_EDGES;

    char* ws = (char*)d_ws;
    size_t off = 0;
    auto alloc = [&](size_t bytes) -> void* {
        void* p = ws + off;
        off = (off + bytes + 255) & ~(size_t)255;
        return p;
    };
    int*   cnt     = (int*)  alloc((size_t)N_NODES * 4);
    int*   rowptr  = (int*)  alloc((size_t)(N_NODES + 1) * 4);
    int*   fill    = (int*)  alloc((size_t)N_NODES * 4);
    int*   bsum    = (int*)  alloc(512 * 4);
    float* dis     = (float*)alloc((size_t)N_NODES * 4);
    int*   col     = (int*)  alloc((size_t)N_EDGES * 4);
    float* wgt     = (float*)alloc((size_t)N_EDGES * 4);
    float* hbuf    = (float*)alloc((size_t)N_NODES * HDIM * 4);
    float* hwbuf   = (float*)alloc((size_t)N_NODES * HDIM * 4);
    float* partial = (float*)alloc(256 * 64 * 4);

    hipMemsetAsync(cnt,  0, (size_t)N_NODES * 4, stream);
    hipMemsetAsync(fill, 0, (size_t)N_NODES * 4, stream);

    int eb = (N_EDGES + 255) / 256;
    int nb = (N_NODES + 255) / 256;   // 391 (< 512, fits k_scan2)
    k_hist   <<<eb, 256, 0, stream>>>(dstp, cnt);
    k_dis    <<<nb, 256, 0, stream>>>(cnt, dis);
    k_scan1  <<<nb, 256, 0, stream>>>(cnt, rowptr, bsum);
    k_scan2  <<<1, 512, 0, stream>>>(bsum, nb, rowptr);
    k_scan3  <<<nb, 256, 0, stream>>>(rowptr, bsum);
    k_scatter<<<eb, 256, 0, stream>>>(srcp, dstp, rowptr, fill, dis, col, wgt);

    int rb = (N_NODES + 3) / 4;       // 25000 blocks, 4 nodes (waves) per block
    k_embed<<<rb, 256, 0, stream>>>(x, w_node, b_node, hbuf);
    for (int l = 0; l < 3; ++l) {
        k_gemm64<<<rb, 256, 0, stream>>>(hbuf, w_c[l], hwbuf);
        k_pull  <<<rb, 256, 0, stream>>>(hwbuf, rowptr, col, wgt, dis, b_c[l], hbuf);
    }
    k_mean <<<256, 256, 0, stream>>>(hbuf, partial);
    k_final<<<1, 64, 0, stream>>>(partial, 256, gfeat, w_glob, b_glob,
                                  w_fc1, b_fc1, w_fc2, b_fc2, out);
}